// Round 5
// baseline (261.186 us; speedup 1.0000x reference)
//
#include <hip/hip_runtime.h>
#include <hip/hip_bf16.h>

typedef __bf16 bf16x8 __attribute__((ext_vector_type(8)));
typedef __bf16 bf16x4 __attribute__((ext_vector_type(4)));
typedef float f32x4 __attribute__((ext_vector_type(4)));
typedef unsigned int u32;
typedef __attribute__((address_space(3))) u32 lds_u32_t;
typedef __attribute__((address_space(1))) u32 glb_u32_t;

#define MROWS 8192      // B*S
#define NEXP 4352       // 2*QK + 2*EXPAND
#define DDIM 1024
#define EDIM 2048

#define S_BAR() asm volatile("s_barrier" ::: "memory")
#define S_VM(n) asm volatile("s_waitcnt vmcnt(" #n ")" ::: "memory")
#define S_LGKM0() asm volatile("s_waitcnt lgkmcnt(0)" ::: "memory")

__device__ __forceinline__ void async16(const void* g, void* l) {
  __builtin_amdgcn_global_load_lds((const glb_u32_t*)g, (lds_u32_t*)l, 16, 0, 0);
}

// ---------------- LayerNorm + bf16 cast ----------------
__global__ __launch_bounds__(256) void ln_kernel(const float* __restrict__ x,
                                                 const float* __restrict__ wgt,
                                                 __bf16* __restrict__ xn) {
  const int row = blockIdx.x;
  const int t = threadIdx.x;
  const float4 v = ((const float4*)(x + (size_t)row * DDIM))[t];
  float s = v.x + v.y + v.z + v.w;
  float ss = v.x * v.x + v.y * v.y + v.z * v.z + v.w * v.w;
  #pragma unroll
  for (int o = 32; o > 0; o >>= 1) {
    s += __shfl_down(s, o);
    ss += __shfl_down(ss, o);
  }
  __shared__ float red[8];
  const int lane = t & 63, wv = t >> 6;
  if (lane == 0) { red[wv] = s; red[4 + wv] = ss; }
  __syncthreads();
  s = red[0] + red[1] + red[2] + red[3];
  ss = red[4] + red[5] + red[6] + red[7];
  const float mu = s * (1.0f / 1024.0f);
  const float rstd = rsqrtf(ss * (1.0f / 1024.0f) - mu * mu + 1e-5f);
  const float4 w4 = ((const float4*)wgt)[t];
  bf16x4 o;
  o[0] = (__bf16)((v.x - mu) * rstd * w4.x);
  o[1] = (__bf16)((v.y - mu) * rstd * w4.y);
  o[2] = (__bf16)((v.z - mu) * rstd * w4.z);
  o[3] = (__bf16)((v.w - mu) * rstd * w4.w);
  ((bf16x4*)(xn + (size_t)row * DDIM))[t] = o;
}

// ---------------- fp32 -> bf16 weight cast ----------------
__global__ __launch_bounds__(256) void cast_kernel(const float* __restrict__ src,
                                                   __bf16* __restrict__ dst, int n4) {
  const int i = blockIdx.x * 256 + threadIdx.x;
  if (i < n4) {
    const float4 v = ((const float4*)src)[i];
    bf16x4 o;
    o[0] = (__bf16)v.x; o[1] = (__bf16)v.y; o[2] = (__bf16)v.z; o[3] = (__bf16)v.w;
    ((bf16x4*)dst)[i] = o;
  }
}

// ------------- small m97-style GEMM (for the skinny q/k columns) -------------
__global__ __launch_bounds__(256) void gemm_bt(const __bf16* __restrict__ A,
                                               const __bf16* __restrict__ Bt,
                                               __bf16* __restrict__ Cout,
                                               int Ndim, int Kdim, int coff) {
  __shared__ __bf16 As[128 * 32];
  __shared__ __bf16 Bs[128 * 32];
  const int t = threadIdx.x;
  const int lane = t & 63;
  const int w = t >> 6;
  const int wm = w >> 1, wn = w & 1;
  const int m0 = blockIdx.x * 128;
  const int n0 = blockIdx.y * 128;

  f32x4 acc[4][4] = {};

  const int cA = w * 2;
  const int sr = cA * 16 + (lane >> 2);
  const int sc = (lane & 3) * 8;
  const __bf16* gA0 = A + (size_t)(m0 + sr) * Kdim + sc;
  const __bf16* gA1 = A + (size_t)(m0 + sr + 16) * Kdim + sc;
  const __bf16* gB0 = Bt + (size_t)(n0 + sr) * Kdim + sc;
  const __bf16* gB1 = Bt + (size_t)(n0 + sr + 16) * Kdim + sc;
  __bf16* lA0 = As + cA * 512;
  __bf16* lA1 = As + (cA + 1) * 512;
  __bf16* lB0 = Bs + cA * 512;
  __bf16* lB1 = Bs + (cA + 1) * 512;

  const int lr = lane & 15;
  const int lk = (lane >> 4) * 8;
  const int nk = Kdim >> 5;

  for (int kt = 0; kt < nk; ++kt) {
    __syncthreads();
    const int ko = kt * 32;
    async16(gA0 + ko, lA0);
    async16(gA1 + ko, lA1);
    async16(gB0 + ko, lB0);
    async16(gB1 + ko, lB1);
    __syncthreads();
    bf16x8 a[4], b[4];
    #pragma unroll
    for (int i = 0; i < 4; ++i)
      a[i] = *(const bf16x8*)&As[(wm * 64 + i * 16 + lr) * 32 + lk];
    #pragma unroll
    for (int i = 0; i < 4; ++i)
      b[i] = *(const bf16x8*)&Bs[(wn * 64 + i * 16 + lr) * 32 + lk];
    #pragma unroll
    for (int i = 0; i < 4; ++i)
      #pragma unroll
      for (int j = 0; j < 4; ++j)
        acc[i][j] = __builtin_amdgcn_mfma_f32_16x16x32_bf16(a[i], b[j], acc[i][j], 0, 0, 0);
  }

  #pragma unroll
  for (int i = 0; i < 4; ++i) {
    const int rbase = m0 + wm * 64 + i * 16 + ((lane >> 4) << 2);
    #pragma unroll
    for (int j = 0; j < 4; ++j) {
      const int col = coff + n0 + wn * 64 + j * 16 + (lane & 15);
      #pragma unroll
      for (int r = 0; r < 4; ++r)
        Cout[(size_t)(rbase + r) * Ndim + col] = (__bf16)acc[i][j][r];
    }
  }
}

// -------- deep-pipelined MFMA GEMM, operands read ONE SUB-PHASE AHEAD --------
// BM x 256 tile, BK=64, 512 threads (8 waves, 2Mx4N), NBUF-buffered swizzled LDS.
// Sub-phase = 8 MFMA; per sub: [issue next sub's ds_reads + staging -> s_barrier
// -> MFMA on regs loaded last sub]. lgkmcnt(0) before last sub's barrier closes
// the cross-wave WAR on buffer reuse; counted vmcnt at tile end only.
// EPI=0: bf16 store at col offset coff. EPI=1: fp32 store = resid + acc.
template <int BM, int EPI>
__global__ __launch_bounds__(512, 2) void gemmdp(const __bf16* __restrict__ A,
                                                 const __bf16* __restrict__ Bt,
                                                 void* __restrict__ Cout,
                                                 const float* __restrict__ resid,
                                                 int Ndim, int Kdim, int ntiles, int coff) {
  constexpr int MF = BM / 32;          // m-frags per wave (8 / 4)
  constexpr int NSUB = MF;             // sub-phases per K-tile (8 / 4)
  constexpr int NPAIR = MF / 2;        // a-pairs per kq (4 / 2)
  constexpr int ASZ = BM * 128;        // bytes per A buffer
  constexpr int BSZ = 256 * 128;       // bytes per B buffer
  constexpr int CA = BM / 64;          // A chunks per tile (4 / 2)
  constexpr int NBUF = (BM == 128) ? 3 : 2;
  __shared__ alignas(16) __bf16 As[NBUF * BM * 64];
  __shared__ alignas(16) __bf16 Bs[NBUF * 256 * 64];

  const int tid = threadIdx.x;
  const int lane = tid & 63;
  const int w = tid >> 6;
  const int wm = w >> 2, wn = w & 3;

  const int qq = gridDim.x >> 3;
  const int wgid = (blockIdx.x & 7) * qq + (blockIdx.x >> 3);
  const int m0 = (wgid / ntiles) * BM;
  const int n0 = (wgid % ntiles) * 256;

  f32x4 acc[MF][4] = {};

  // staging map: LDS(row, c16) holds global(row, c16 ^ ((row&7)<<4))
  const int rowS = tid >> 3;
  const int kbS = ((tid & 7) * 16) ^ ((rowS & 7) << 4);
  const size_t K2 = (size_t)Kdim * 2;
  const char* gA = (const char*)A + (size_t)(m0 + rowS) * K2 + kbS;
  const char* gB = (const char*)Bt + (size_t)(n0 + rowS) * K2 + kbS;
  char* lA = (char*)As;
  char* lB = (char*)Bs;

  const int lr = lane & 15;
  const int hi = lane >> 4;
  const int kxor = (lr & 7) << 4;
  const int NT = Kdim >> 6;

  auto rdA = [&](const char* base, int frag, int kq) -> bf16x8 {
    return *(const bf16x8*)(base + (wm * (BM / 2) + frag * 16 + lr) * 128 +
                            ((hi * 16 + kq * 64) ^ kxor));
  };
  auto rdB = [&](const char* base, int frag, int kq) -> bf16x8 {
    return *(const bf16x8*)(base + (wn * 64 + frag * 16 + lr) * 128 +
                            ((hi * 16 + kq * 64) ^ kxor));
  };
  auto stgA = [&](int tt, int bw, int c) {
    async16(gA + (size_t)tt * 128 + (size_t)c * 64 * K2, lA + bw * ASZ + c * 8192 + tid * 16);
  };
  auto stgB = [&](int tt, int bw, int c) {
    async16(gB + (size_t)tt * 128 + (size_t)c * 64 * K2, lB + bw * BSZ + c * 8192 + tid * 16);
  };

  // prologue: stage tile 0 (and tile 1 if triple-buffered)
  #pragma unroll
  for (int c = 0; c < CA; ++c) stgA(0, 0, c);
  #pragma unroll
  for (int c = 0; c < 4; ++c) stgB(0, 0, c);
  if constexpr (NBUF == 3) {
    #pragma unroll
    for (int c = 0; c < CA; ++c) stgA(1, 1, c);
    #pragma unroll
    for (int c = 0; c < 4; ++c) stgB(1, 1, c);
    S_VM(6);
  } else {
    S_VM(0);
  }
  S_BAR();

  bf16x8 aR[2][2], bR[2][4];
  #pragma unroll
  for (int ni = 0; ni < 4; ++ni) bR[0][ni] = rdB(lB, ni, 0);
  aR[0][0] = rdA(lA, 0, 0);
  aR[0][1] = rdA(lA, 1, 0);

  int bufR = 0, bufW = NBUF - 1;
  for (int t = 0; t < NT; ++t) {
    const char* lAr = lA + bufR * ASZ;
    const char* lBr = lB + bufR * BSZ;
    const int tS = t + NBUF - 1;           // tile index being staged this tile
    const bool st = tS < NT;
    const bool prd = (t + 1) < NT;         // pre-read next tile at last sub
    const int bufN = (bufR + 1 == NBUF) ? 0 : bufR + 1;

    #pragma unroll
    for (int s = 0; s < NSUB; ++s) {
      const int kq = s / NPAIR;
      const int cur = s & 1, nxt = cur ^ 1;

      // --- issue ds_reads for sub s+1 (hidden under this sub's MFMA) ---
      if (s + 1 < NSUB) {
        const int kq1 = (s + 1) / NPAIR;
        const int pr1 = (s + 1) % NPAIR;
        aR[nxt][0] = rdA(lAr, 2 * pr1, kq1);
        aR[nxt][1] = rdA(lAr, 2 * pr1 + 1, kq1);
      }
      if constexpr (BM == 256) {
        if (s < 4) bR[1][s] = rdB(lBr, s, 1);
      } else {
        if (s < 2) {
          bR[1][2 * s] = rdB(lBr, 2 * s, 1);
          bR[1][2 * s + 1] = rdB(lBr, 2 * s + 1, 1);
        }
      }
      // --- staging, spread across early subs ---
      if (st) {
        if constexpr (BM == 256) {
          if (s < 4) { stgA(tS, bufW, s); stgB(tS, bufW, s); }
        } else {
          if (s == 0)      { stgA(tS, bufW, 0); stgB(tS, bufW, 0); }
          else if (s == 1) { stgA(tS, bufW, 1); stgB(tS, bufW, 1); }
          else if (s == 2) { stgB(tS, bufW, 2); stgB(tS, bufW, 3); }
        }
      }
      // --- tile boundary: wait staged tile t+1, pre-read its first operands ---
      if (s == NSUB - 1) {
        if constexpr (NBUF == 3) {
          if (st) { S_VM(6); } else { S_VM(0); }
        } else {
          S_VM(0);
        }
        if (prd) {
          const char* nAr = lA + bufN * ASZ;
          const char* nBr = lB + bufN * BSZ;
          #pragma unroll
          for (int ni = 0; ni < 4; ++ni) bR[0][ni] = rdB(nBr, ni, 0);
          aR[0][0] = rdA(nAr, 0, 0);
          aR[0][1] = rdA(nAr, 1, 0);
        }
        S_LGKM0();   // all our LDS reads done before anyone re-stages these buffers
      }
      S_BAR();
      __builtin_amdgcn_s_setprio(1);
      const int mi0 = 2 * (s % NPAIR);
      #pragma unroll
      for (int j = 0; j < 2; ++j)
        #pragma unroll
        for (int ni = 0; ni < 4; ++ni)
          acc[mi0 + j][ni] =
              __builtin_amdgcn_mfma_f32_16x16x32_bf16(aR[cur][j], bR[kq][ni], acc[mi0 + j][ni], 0, 0, 0);
      __builtin_amdgcn_s_setprio(0);
    }
    bufR = bufN;
    bufW = (bufW + 1 == NBUF) ? 0 : bufW + 1;
  }

  // epilogue: C/D layout row=(lane>>4)*4+reg, col=lane&15
  #pragma unroll
  for (int mi = 0; mi < MF; ++mi) {
    const int rbase = m0 + wm * (BM / 2) + mi * 16 + ((lane >> 4) << 2);
    #pragma unroll
    for (int ni = 0; ni < 4; ++ni) {
      const int col = coff + n0 + wn * 64 + ni * 16 + (lane & 15);
      #pragma unroll
      for (int r = 0; r < 4; ++r) {
        const size_t off = (size_t)(rbase + r) * Ndim + col;
        if constexpr (EPI == 0) ((__bf16*)Cout)[off] = (__bf16)acc[mi][ni][r];
        else                    ((float*)Cout)[off] = resid[off] + acc[mi][ni][r];
      }
    }
  }
}

// ---------------- GEGLU: gl / v from h ----------------
__global__ __launch_bounds__(256) void geglu_kernel(const __bf16* __restrict__ h,
                                                    __bf16* __restrict__ fused,
                                                    __bf16* __restrict__ vbuf) {
  const int idx = blockIdx.x * 256 + threadIdx.x;
  const int row = idx >> 8;
  const int col = (idx & 255) * 8;
  const bf16x8 lin = *(const bf16x8*)&h[(size_t)row * NEXP + 256 + col];
  const bf16x8 pre = *(const bf16x8*)&h[(size_t)row * NEXP + 2304 + col];
  bf16x8 o;
  #pragma unroll
  for (int j = 0; j < 8; ++j) {
    const float p = (float)pre[j];
    const float g = 0.5f * p * (1.0f + erff(p * 0.70710678118f));
    o[j] = (__bf16)((float)lin[j] * g);
  }
  if (col < 1024)
    *(bf16x8*)&fused[(size_t)row * EDIM + col] = o;
  else
    *(bf16x8*)&vbuf[(size_t)row * 1024 + (col - 1024)] = o;
}

// ---------------- sliding-window attention (W=32), 1 wave per (b,head,s) ----------
__global__ __launch_bounds__(256) void attn_kernel(const __bf16* __restrict__ h,
                                                   const __bf16* __restrict__ vbuf,
                                                   __bf16* __restrict__ fused,
                                                   const float* __restrict__ pbm) {
  const int gw = blockIdx.x * 4 + (threadIdx.x >> 6);
  const int lane = threadIdx.x & 63;
  const int s = gw & 1023;
  const int head = (gw >> 10) & 3;
  const int b = gw >> 12;

  const float p = pbm[0];
  const float sp = (p > 20.0f) ? p : log1pf(expf(p));

  const size_t rowq = (size_t)(b * 1024 + s);
  float q[32];
  const bf16x8* qp = (const bf16x8*)&h[rowq * NEXP + head * 32];
  #pragma unroll
  for (int c = 0; c < 4; ++c) {
    const bf16x8 tq = qp[c];
    #pragma unroll
    for (int j = 0; j < 8; ++j) q[c * 8 + j] = (float)tq[j];
  }

  const int jj = lane & 31;
  const int sk = s - 31 + jj;
  const int skc = (sk < 0) ? 0 : sk;
  float dot = 0.0f;
  const bf16x8* kp = (const bf16x8*)&h[(size_t)(b * 1024 + skc) * NEXP + 128 + head * 32];
  #pragma unroll
  for (int c = 0; c < 4; ++c) {
    const bf16x8 tk = kp[c];
    #pragma unroll
    for (int j = 0; j < 8; ++j) dot += q[c * 8 + j] * (float)tk[j];
  }
  float score = (sk >= 0) ? (dot * 0.1767766953f + sp * (float)(sk - s)) : -1e30f;

  float mx = score;
  #pragma unroll
  for (int o = 16; o > 0; o >>= 1) mx = fmaxf(mx, __shfl_xor(mx, o));
  const float wgt = expf(score - mx);
  float sum = wgt;
  #pragma unroll
  for (int o = 16; o > 0; o >>= 1) sum += __shfl_xor(sum, o);

  float a0 = 0.f, a1 = 0.f, a2 = 0.f, a3 = 0.f;
  const __bf16* vb = vbuf + head * 256 + lane * 4;
  for (int j2 = 0; j2 < 32; ++j2) {
    const int sv = s - 31 + j2;
    if (sv < 0) continue;
    const float wj = __shfl(wgt, j2);
    const bf16x4 vv = *(const bf16x4*)&vb[(size_t)(b * 1024 + sv) * 1024];
    a0 += wj * (float)vv[0];
    a1 += wj * (float)vv[1];
    a2 += wj * (float)vv[2];
    a3 += wj * (float)vv[3];
  }
  const float inv = 1.0f / sum;
  bf16x4 o;
  o[0] = (__bf16)(a0 * inv);
  o[1] = (__bf16)(a1 * inv);
  o[2] = (__bf16)(a2 * inv);
  o[3] = (__bf16)(a3 * inv);
  *(bf16x4*)&fused[rowq * EDIM + 1024 + head * 256 + lane * 4] = o;
}

// ---------------- host launch ----------------
extern "C" void kernel_launch(void* const* d_in, const int* in_sizes, int n_in,
                              void* d_out, int out_size, void* d_ws, size_t ws_size,
                              hipStream_t stream) {
  const float* x = (const float*)d_in[0];
  const float* norm_w = (const float*)d_in[2];
  const float* expand_w = (const float*)d_in[3];
  const float* project_w = (const float*)d_in[4];
  const float* pbm = (const float*)d_in[5];
  float* out = (float*)d_out;

  char* ws = (char*)d_ws;
  __bf16* xn    = (__bf16*)(ws);                 // 16,777,216
  __bf16* wexp  = (__bf16*)(ws + 16777216);      //  8,912,896
  __bf16* wproj = (__bf16*)(ws + 25690112);      //  4,194,304
  __bf16* h     = (__bf16*)(ws + 29884416);      // 71,303,168
  __bf16* fused = (__bf16*)(ws + 101187584);     // 33,554,432
  __bf16* vbuf  = (__bf16*)(ws + 134742016);     // 16,777,216

  ln_kernel<<<MROWS, 256, 0, stream>>>(x, norm_w, xn);
  cast_kernel<<<4352, 256, 0, stream>>>(expand_w, wexp, 4456448 / 4);
  cast_kernel<<<2048, 256, 0, stream>>>(project_w, wproj, 2097152 / 4);
  // q/k columns: M=8192, N=256, K=1024
  gemm_bt<<<dim3(64, 2), 256, 0, stream>>>(xn, wexp, h, NEXP, DDIM, 0);
  // lin|pre columns: M=8192, N=4096, K=1024 -> 512 blocks (2.0 rounds)
  gemmdp<256, 0><<<512, 512, 0, stream>>>(xn, wexp + 256 * DDIM, (void*)h, nullptr,
                                          NEXP, DDIM, 16, 256);
  geglu_kernel<<<MROWS, 256, 0, stream>>>(h, fused, vbuf);
  attn_kernel<<<MROWS, 256, 0, stream>>>(h, vbuf, fused, pbm);
  // project: M=8192, N=1024, K=2048 -> 256 blocks (1.0 round)
  gemmdp<128, 1><<<256, 512, 0, stream>>>(fused, wproj, (void*)out, x, DDIM, EDIM, 4, 0);
}

// Round 6
// 236.168 us; speedup vs baseline: 1.1059x; 1.1059x over previous
//
#include <hip/hip_runtime.h>
#include <hip/hip_bf16.h>

typedef __bf16 bf16x8 __attribute__((ext_vector_type(8)));
typedef __bf16 bf16x4 __attribute__((ext_vector_type(4)));
typedef float f32x4 __attribute__((ext_vector_type(4)));
typedef unsigned int u32;
typedef __attribute__((address_space(3))) u32 lds_u32_t;
typedef __attribute__((address_space(1))) u32 glb_u32_t;

#define MROWS 8192      // B*S
#define NEXP 4352       // 2*QK + 2*EXPAND
#define DDIM 1024
#define EDIM 2048

#define S_BAR() asm volatile("s_barrier" ::: "memory")
#define S_VM0() asm volatile("s_waitcnt vmcnt(0)" ::: "memory")
#define SCHED_PIN() __builtin_amdgcn_sched_barrier(0)

__device__ __forceinline__ void async16(const void* g, void* l) {
  __builtin_amdgcn_global_load_lds((const glb_u32_t*)g, (lds_u32_t*)l, 16, 0, 0);
}

// ---------------- LayerNorm + bf16 cast ----------------
__global__ __launch_bounds__(256) void ln_kernel(const float* __restrict__ x,
                                                 const float* __restrict__ wgt,
                                                 __bf16* __restrict__ xn) {
  const int row = blockIdx.x;
  const int t = threadIdx.x;
  const float4 v = ((const float4*)(x + (size_t)row * DDIM))[t];
  float s = v.x + v.y + v.z + v.w;
  float ss = v.x * v.x + v.y * v.y + v.z * v.z + v.w * v.w;
  #pragma unroll
  for (int o = 32; o > 0; o >>= 1) {
    s += __shfl_down(s, o);
    ss += __shfl_down(ss, o);
  }
  __shared__ float red[8];
  const int lane = t & 63, wv = t >> 6;
  if (lane == 0) { red[wv] = s; red[4 + wv] = ss; }
  __syncthreads();
  s = red[0] + red[1] + red[2] + red[3];
  ss = red[4] + red[5] + red[6] + red[7];
  const float mu = s * (1.0f / 1024.0f);
  const float rstd = rsqrtf(ss * (1.0f / 1024.0f) - mu * mu + 1e-5f);
  const float4 w4 = ((const float4*)wgt)[t];
  bf16x4 o;
  o[0] = (__bf16)((v.x - mu) * rstd * w4.x);
  o[1] = (__bf16)((v.y - mu) * rstd * w4.y);
  o[2] = (__bf16)((v.z - mu) * rstd * w4.z);
  o[3] = (__bf16)((v.w - mu) * rstd * w4.w);
  ((bf16x4*)(xn + (size_t)row * DDIM))[t] = o;
}

// ---------------- fp32 -> bf16 weight cast ----------------
__global__ __launch_bounds__(256) void cast_kernel(const float* __restrict__ src,
                                                   __bf16* __restrict__ dst, int n4) {
  const int i = blockIdx.x * 256 + threadIdx.x;
  if (i < n4) {
    const float4 v = ((const float4*)src)[i];
    bf16x4 o;
    o[0] = (__bf16)v.x; o[1] = (__bf16)v.y; o[2] = (__bf16)v.z; o[3] = (__bf16)v.w;
    ((bf16x4*)dst)[i] = o;
  }
}

// ------------- small m97-style GEMM (for the skinny q/k columns) -------------
__global__ __launch_bounds__(256) void gemm_bt(const __bf16* __restrict__ A,
                                               const __bf16* __restrict__ Bt,
                                               __bf16* __restrict__ Cout,
                                               int Ndim, int Kdim, int coff) {
  __shared__ __bf16 As[128 * 32];
  __shared__ __bf16 Bs[128 * 32];
  const int t = threadIdx.x;
  const int lane = t & 63;
  const int w = t >> 6;
  const int wm = w >> 1, wn = w & 1;
  const int m0 = blockIdx.x * 128;
  const int n0 = blockIdx.y * 128;

  f32x4 acc[4][4] = {};

  const int cA = w * 2;
  const int sr = cA * 16 + (lane >> 2);
  const int sc = (lane & 3) * 8;
  const __bf16* gA0 = A + (size_t)(m0 + sr) * Kdim + sc;
  const __bf16* gA1 = A + (size_t)(m0 + sr + 16) * Kdim + sc;
  const __bf16* gB0 = Bt + (size_t)(n0 + sr) * Kdim + sc;
  const __bf16* gB1 = Bt + (size_t)(n0 + sr + 16) * Kdim + sc;
  __bf16* lA0 = As + cA * 512;
  __bf16* lA1 = As + (cA + 1) * 512;
  __bf16* lB0 = Bs + cA * 512;
  __bf16* lB1 = Bs + (cA + 1) * 512;

  const int lr = lane & 15;
  const int lk = (lane >> 4) * 8;
  const int nk = Kdim >> 5;

  for (int kt = 0; kt < nk; ++kt) {
    __syncthreads();
    const int ko = kt * 32;
    async16(gA0 + ko, lA0);
    async16(gA1 + ko, lA1);
    async16(gB0 + ko, lB0);
    async16(gB1 + ko, lB1);
    __syncthreads();
    bf16x8 a[4], b[4];
    #pragma unroll
    for (int i = 0; i < 4; ++i)
      a[i] = *(const bf16x8*)&As[(wm * 64 + i * 16 + lr) * 32 + lk];
    #pragma unroll
    for (int i = 0; i < 4; ++i)
      b[i] = *(const bf16x8*)&Bs[(wn * 64 + i * 16 + lr) * 32 + lk];
    #pragma unroll
    for (int i = 0; i < 4; ++i)
      #pragma unroll
      for (int j = 0; j < 4; ++j)
        acc[i][j] = __builtin_amdgcn_mfma_f32_16x16x32_bf16(a[i], b[j], acc[i][j], 0, 0, 0);
  }

  #pragma unroll
  for (int i = 0; i < 4; ++i) {
    const int rbase = m0 + wm * 64 + i * 16 + ((lane >> 4) << 2);
    #pragma unroll
    for (int j = 0; j < 4; ++j) {
      const int col = coff + n0 + wn * 64 + j * 16 + (lane & 15);
      #pragma unroll
      for (int r = 0; r < 4; ++r)
        Cout[(size_t)(rbase + r) * Ndim + col] = (__bf16)acc[i][j][r];
    }
  }
}

// ------- full-tile register-pipelined MFMA GEMM, C = A * Bt^T --------
// BM x 256 tile, BK=64, 512 threads (8 waves, 2Mx4N), double-buffered
// XOR-swizzled LDS. Per K-tile: issue ALL 24 fragment ds_reads (pinned),
// then ALL staging DMAs (pinned), then two 32-MFMA clusters whose operand
// waits are compiler-inserted counted lgkmcnt -> kq1's LDS service overlaps
// kq0's MFMA. One vmcnt(0)+barrier per tile.
// EPI=0: bf16 store at col offset coff. EPI=1: fp32 store = resid + acc.
template <int BM, int EPI>
__global__ __launch_bounds__(512, 2) void gemmrp(const __bf16* __restrict__ A,
                                                 const __bf16* __restrict__ Bt,
                                                 void* __restrict__ Cout,
                                                 const float* __restrict__ resid,
                                                 int Ndim, int Kdim, int ntiles, int coff) {
  constexpr int MF = BM / 32;          // A-frags per kq (8 / 4)
  constexpr int ASZ = BM * 128;        // bytes per A buffer
  constexpr int BSZ = 256 * 128;       // bytes per B buffer
  constexpr int CA = BM / 64;          // A stage chunks per tile (4 / 2)
  __shared__ alignas(16) __bf16 As[2 * BM * 64];
  __shared__ alignas(16) __bf16 Bs[2 * 256 * 64];

  const int tid = threadIdx.x;
  const int lane = tid & 63;
  const int w = tid >> 6;
  const int wm = w >> 2, wn = w & 3;

  const int qq = gridDim.x >> 3;
  const int wgid = (blockIdx.x & 7) * qq + (blockIdx.x >> 3);
  const int m0 = (wgid / ntiles) * BM;
  const int n0 = (wgid % ntiles) * 256;

  f32x4 acc[MF][4] = {};

  // staging map: LDS(row, c16) holds global(row, c16 ^ ((row&7)<<4))
  const int rowS = tid >> 3;
  const int kbS = ((tid & 7) * 16) ^ ((rowS & 7) << 4);
  const size_t K2 = (size_t)Kdim * 2;
  const char* gA = (const char*)A + (size_t)(m0 + rowS) * K2 + kbS;
  const char* gB = (const char*)Bt + (size_t)(n0 + rowS) * K2 + kbS;
  char* lA = (char*)As;
  char* lB = (char*)Bs;

  const int lr = lane & 15;
  const int hi = lane >> 4;
  const int kxor = (lr & 7) << 4;
  const int k0 = (hi * 16) ^ kxor;           // kq=0 byte offset
  const int k1 = ((hi * 16) | 64) ^ kxor;    // kq=1 byte offset
  const int rowA = (wm * (BM / 2) + lr) * 128;
  const int rowB = (wn * 64 + lr) * 128;
  const int NT = Kdim >> 6;

  // prologue: stage tile 0 into buf 0
  #pragma unroll
  for (int c = 0; c < CA; ++c) async16(gA + (size_t)c * 64 * K2, lA + c * 8192 + tid * 16);
  #pragma unroll
  for (int c = 0; c < 4; ++c) async16(gB + (size_t)c * 64 * K2, lB + c * 8192 + tid * 16);
  S_VM0();
  S_BAR();

  for (int t = 0; t < NT; ++t) {
    const int buf = t & 1;
    const char* pA0 = lA + buf * ASZ + rowA + k0;
    const char* pA1 = lA + buf * ASZ + rowA + k1;
    const char* pB0 = lB + buf * BSZ + rowB + k0;
    const char* pB1 = lB + buf * BSZ + rowB + k1;

    bf16x8 b0[4], a0[MF], b1[4], a1[MF];
    // -------- group 1: kq0 reads (12 / 8) --------
    #pragma unroll
    for (int ni = 0; ni < 4; ++ni) b0[ni] = *(const bf16x8*)(pB0 + ni * 2048);
    #pragma unroll
    for (int mi = 0; mi < MF; ++mi) a0[mi] = *(const bf16x8*)(pA0 + mi * 2048);
    SCHED_PIN();
    // -------- group 2: kq1 reads (12 / 8) --------
    #pragma unroll
    for (int ni = 0; ni < 4; ++ni) b1[ni] = *(const bf16x8*)(pB1 + ni * 2048);
    #pragma unroll
    for (int mi = 0; mi < MF; ++mi) a1[mi] = *(const bf16x8*)(pA1 + mi * 2048);
    SCHED_PIN();
    // -------- group 3: stage tile t+1 into buf^1 --------
    if (t + 1 < NT) {
      const char* gAt = gA + (size_t)(t + 1) * 128;
      const char* gBt = gB + (size_t)(t + 1) * 128;
      char* lAd = lA + (buf ^ 1) * ASZ + tid * 16;
      char* lBd = lB + (buf ^ 1) * BSZ + tid * 16;
      #pragma unroll
      for (int c = 0; c < CA; ++c) async16(gAt + (size_t)c * 64 * K2, lAd + c * 8192);
      #pragma unroll
      for (int c = 0; c < 4; ++c) async16(gBt + (size_t)c * 64 * K2, lBd + c * 8192);
    }
    SCHED_PIN();
    // -------- MFMA kq0 (compiler inserts counted lgkm waits; kq1 reads
    //          + staging stay in flight and are serviced underneath) --------
    __builtin_amdgcn_s_setprio(1);
    #pragma unroll
    for (int mi = 0; mi < MF; ++mi)
      #pragma unroll
      for (int ni = 0; ni < 4; ++ni)
        acc[mi][ni] = __builtin_amdgcn_mfma_f32_16x16x32_bf16(a0[mi], b0[ni], acc[mi][ni], 0, 0, 0);
    __builtin_amdgcn_s_setprio(0);
    SCHED_PIN();
    // -------- MFMA kq1 --------
    __builtin_amdgcn_s_setprio(1);
    #pragma unroll
    for (int mi = 0; mi < MF; ++mi)
      #pragma unroll
      for (int ni = 0; ni < 4; ++ni)
        acc[mi][ni] = __builtin_amdgcn_mfma_f32_16x16x32_bf16(a1[mi], b1[ni], acc[mi][ni], 0, 0, 0);
    __builtin_amdgcn_s_setprio(0);
    SCHED_PIN();
    // tile boundary: next tile's data must be in LDS; all our reads are
    // already drained (every read consumed by an MFMA above).
    if (t + 1 < NT) S_VM0();
    S_BAR();
  }

  // epilogue: C/D layout row=(lane>>4)*4+reg, col=lane&15
  #pragma unroll
  for (int mi = 0; mi < MF; ++mi) {
    const int rbase = m0 + wm * (BM / 2) + mi * 16 + ((lane >> 4) << 2);
    #pragma unroll
    for (int ni = 0; ni < 4; ++ni) {
      const int col = coff + n0 + wn * 64 + ni * 16 + (lane & 15);
      #pragma unroll
      for (int r = 0; r < 4; ++r) {
        const size_t off = (size_t)(rbase + r) * Ndim + col;
        if constexpr (EPI == 0) ((__bf16*)Cout)[off] = (__bf16)acc[mi][ni][r];
        else                    ((float*)Cout)[off] = resid[off] + acc[mi][ni][r];
      }
    }
  }
}

// ---------------- GEGLU: gl / v from h ----------------
__global__ __launch_bounds__(256) void geglu_kernel(const __bf16* __restrict__ h,
                                                    __bf16* __restrict__ fused,
                                                    __bf16* __restrict__ vbuf) {
  const int idx = blockIdx.x * 256 + threadIdx.x;
  const int row = idx >> 8;
  const int col = (idx & 255) * 8;
  const bf16x8 lin = *(const bf16x8*)&h[(size_t)row * NEXP + 256 + col];
  const bf16x8 pre = *(const bf16x8*)&h[(size_t)row * NEXP + 2304 + col];
  bf16x8 o;
  #pragma unroll
  for (int j = 0; j < 8; ++j) {
    const float p = (float)pre[j];
    const float g = 0.5f * p * (1.0f + erff(p * 0.70710678118f));
    o[j] = (__bf16)((float)lin[j] * g);
  }
  if (col < 1024)
    *(bf16x8*)&fused[(size_t)row * EDIM + col] = o;
  else
    *(bf16x8*)&vbuf[(size_t)row * 1024 + (col - 1024)] = o;
}

// ---------------- sliding-window attention (W=32), 1 wave per (b,head,s) ----------
__global__ __launch_bounds__(256) void attn_kernel(const __bf16* __restrict__ h,
                                                   const __bf16* __restrict__ vbuf,
                                                   __bf16* __restrict__ fused,
                                                   const float* __restrict__ pbm) {
  const int gw = blockIdx.x * 4 + (threadIdx.x >> 6);
  const int lane = threadIdx.x & 63;
  const int s = gw & 1023;
  const int head = (gw >> 10) & 3;
  const int b = gw >> 12;

  const float p = pbm[0];
  const float sp = (p > 20.0f) ? p : log1pf(expf(p));

  const size_t rowq = (size_t)(b * 1024 + s);
  float q[32];
  const bf16x8* qp = (const bf16x8*)&h[rowq * NEXP + head * 32];
  #pragma unroll
  for (int c = 0; c < 4; ++c) {
    const bf16x8 tq = qp[c];
    #pragma unroll
    for (int j = 0; j < 8; ++j) q[c * 8 + j] = (float)tq[j];
  }

  const int jj = lane & 31;
  const int sk = s - 31 + jj;
  const int skc = (sk < 0) ? 0 : sk;
  float dot = 0.0f;
  const bf16x8* kp = (const bf16x8*)&h[(size_t)(b * 1024 + skc) * NEXP + 128 + head * 32];
  #pragma unroll
  for (int c = 0; c < 4; ++c) {
    const bf16x8 tk = kp[c];
    #pragma unroll
    for (int j = 0; j < 8; ++j) dot += q[c * 8 + j] * (float)tk[j];
  }
  float score = (sk >= 0) ? (dot * 0.1767766953f + sp * (float)(sk - s)) : -1e30f;

  float mx = score;
  #pragma unroll
  for (int o = 16; o > 0; o >>= 1) mx = fmaxf(mx, __shfl_xor(mx, o));
  const float wgt = expf(score - mx);
  float sum = wgt;
  #pragma unroll
  for (int o = 16; o > 0; o >>= 1) sum += __shfl_xor(sum, o);

  float a0 = 0.f, a1 = 0.f, a2 = 0.f, a3 = 0.f;
  const __bf16* vb = vbuf + head * 256 + lane * 4;
  for (int j2 = 0; j2 < 32; ++j2) {
    const int sv = s - 31 + j2;
    if (sv < 0) continue;
    const float wj = __shfl(wgt, j2);
    const bf16x4 vv = *(const bf16x4*)&vb[(size_t)(b * 1024 + sv) * 1024];
    a0 += wj * (float)vv[0];
    a1 += wj * (float)vv[1];
    a2 += wj * (float)vv[2];
    a3 += wj * (float)vv[3];
  }
  const float inv = 1.0f / sum;
  bf16x4 o;
  o[0] = (__bf16)(a0 * inv);
  o[1] = (__bf16)(a1 * inv);
  o[2] = (__bf16)(a2 * inv);
  o[3] = (__bf16)(a3 * inv);
  *(bf16x4*)&fused[rowq * EDIM + 1024 + head * 256 + lane * 4] = o;
}

// ---------------- host launch ----------------
extern "C" void kernel_launch(void* const* d_in, const int* in_sizes, int n_in,
                              void* d_out, int out_size, void* d_ws, size_t ws_size,
                              hipStream_t stream) {
  const float* x = (const float*)d_in[0];
  const float* norm_w = (const float*)d_in[2];
  const float* expand_w = (const float*)d_in[3];
  const float* project_w = (const float*)d_in[4];
  const float* pbm = (const float*)d_in[5];
  float* out = (float*)d_out;

  char* ws = (char*)d_ws;
  __bf16* xn    = (__bf16*)(ws);                 // 16,777,216
  __bf16* wexp  = (__bf16*)(ws + 16777216);      //  8,912,896
  __bf16* wproj = (__bf16*)(ws + 25690112);      //  4,194,304
  __bf16* h     = (__bf16*)(ws + 29884416);      // 71,303,168
  __bf16* fused = (__bf16*)(ws + 101187584);     // 33,554,432
  __bf16* vbuf  = (__bf16*)(ws + 134742016);     // 16,777,216

  ln_kernel<<<MROWS, 256, 0, stream>>>(x, norm_w, xn);
  cast_kernel<<<4352, 256, 0, stream>>>(expand_w, wexp, 4456448 / 4);
  cast_kernel<<<2048, 256, 0, stream>>>(project_w, wproj, 2097152 / 4);
  // q/k columns: M=8192, N=256, K=1024
  gemm_bt<<<dim3(64, 2), 256, 0, stream>>>(xn, wexp, h, NEXP, DDIM, 0);
  // lin|pre columns: M=8192, N=4096, K=1024 -> 512 blocks (2.0 rounds)
  gemmrp<256, 0><<<512, 512, 0, stream>>>(xn, wexp + 256 * DDIM, (void*)h, nullptr,
                                          NEXP, DDIM, 16, 256);
  geglu_kernel<<<MROWS, 256, 0, stream>>>(h, fused, vbuf);
  attn_kernel<<<MROWS, 256, 0, stream>>>(h, vbuf, fused, pbm);
  // project: M=8192, N=1024, K=2048 -> 256 blocks (1.0 round)
  gemmrp<128, 1><<<256, 512, 0, stream>>>(fused, wproj, (void*)out, x, DDIM, EDIM, 4, 0);
}